// Round 4
// baseline (2582.145 us; speedup 1.0000x reference)
//
#include <hip/hip_runtime.h>

// ---------------------------------------------------------------------------
// peepLSTM (B=512,S=256,H=768,E=6,C=10,V=3) — fp16 split MFMA, fence-free sync
//
//  r4 changes vs r3:
//   * W-lo fragments now PERSIST in VGPRs (whi 48 + wlo 48 regs/lane,
//     __launch_bounds__(512,1)) — removes 192 KB/block/step L2 streaming.
//   * Split-phase barrier: f-waves drain own stores -> LDS monotonic counter;
//     4th f-wave fires group flag. Every wave independently polls the 12
//     remote flags then stages its tile share (no all-wave drain barrier).
// ---------------------------------------------------------------------------

typedef _Float16 f16x8 __attribute__((ext_vector_type(8)));
typedef _Float16 f16x4 __attribute__((ext_vector_type(4)));
typedef float    f32x4 __attribute__((ext_vector_type(4)));

#define Hdim  768
#define Bdim  512
#define Sdim  256
#define NSTEP 255
#define Edim  6
#define NCls  10
#define NGRP  16
#define NRB   12
#define GC    32
#define HB    64
#define NKK   24
#define CSTR  776
#define XSTR  260
#define PLANE (Bdim * Hdim)          // fp16 elems per c plane (393216)
#define SCL      4096.0f
#define SCL_INV  2.44140625e-4f      // 2^-12

#define WP_FRAGS   (2 * NRB * 4 * NKK * 64)         // 147456 fragments (16B each)
#define WS_CBUF    0u                               // 2 bufs x 2 planes x PLANE fp16
#define WS_HFIN    (2u * 2u * PLANE * 2u)           // 3,145,728
#define WS_BAR     (WS_HFIN + Bdim * Hdim * 4u)     // 4,718,592
#define WS_WPK     (WS_BAR + 4096u)                 // 4,722,688
#define WS_BAR_BYTES (NGRP * 16u * 4u)              // 1024

__device__ __forceinline__ float sigf(float z) { return 1.0f / (1.0f + __expf(-z)); }

__device__ __forceinline__ f32x4 mf(f16x8 a, f16x8 b, f32x4 c) {
    return __builtin_amdgcn_mfma_f32_16x16x32_f16(a, b, c, 0, 0, 0);
}

// ---------------- prep: split W into fp16 hi / (lo*4096) fragment planes ----
__global__ void __launch_bounds__(256)
prep_w(const float* __restrict__ Wfh, const float* __restrict__ Wih,
       _Float16* __restrict__ wpk)
{
    const int fid  = blockIdx.x * 256 + threadIdx.x;   // 0..147455
    const int lane = fid & 63;
    const int t1   = fid >> 6;            // gi*24 + kk
    const int kk   = t1 % NKK;
    const int gi   = t1 / NKK;            // (gate*12+rb)*4+sub
    const int sub  = gi & 3;
    const int t3   = gi >> 2;
    const int rb   = t3 % NRB;
    const int gate = t3 / NRB;
    const int q = lane >> 4, r = lane & 15;
    const int row = rb * 64 + sub * 16 + r;
    const int col = kk * 32 + q * 8;
    const float* src = (gate ? Wih : Wfh) + (size_t)row * Hdim + col;
    f16x8 hi, lo;
    #pragma unroll
    for (int j = 0; j < 8; ++j) {
        const float v = src[j];
        const _Float16 h = (_Float16)v;
        hi[j] = h;
        lo[j] = (_Float16)((v - (float)h) * SCL);
    }
    *(f16x8*)&wpk[(size_t)fid * 8] = hi;
    *(f16x8*)&wpk[((size_t)WP_FRAGS + fid) * 8] = lo;
}

// ---------------- main persistent kernel ------------------------------------
__global__ void __launch_bounds__(512, 1)
lstm_persist(const int* __restrict__ xk, const float* __restrict__ emb,
             const float* __restrict__ Wfx, const float* __restrict__ bfv,
             const float* __restrict__ Wix, const float* __restrict__ biv,
             const float* __restrict__ Wox, const float* __restrict__ Woh,
             const float* __restrict__ bov,
             const float* __restrict__ Wcx, const float* __restrict__ bcv,
             const float* __restrict__ cinit,
             const _Float16* __restrict__ wpk,
             _Float16* __restrict__ cbuf, float* __restrict__ hfin,
             unsigned int* __restrict__ bar)
{
    __shared__ __align__(16) _Float16 ldsH[GC * CSTR];        // 49,664 B
    __shared__ __align__(16) _Float16 ldsM[GC * CSTR];        // 49,664 B
    __shared__ __align__(16) float    tbl[3 * HB * 4];        //  3,072 B
    __shared__ __align__(16) float    zbuf[HB * GC];          //  8,192 B
    __shared__ __align__(4)  unsigned char xtok[GC * XSTR];   //  8,320 B
    __shared__ int s_flag;
    __shared__ unsigned int fdone;                            // monotonic

    const int tid  = threadIdx.x;
    const int w    = tid >> 6;
    const int lane = tid & 63;
    const int q    = lane >> 4;
    const int r    = lane & 15;
    const int gt   = w >> 2;            // 0 = f-waves, 1 = i-waves
    const int sub  = w & 3;
    const int bid  = blockIdx.x;
    const int g    = bid & 15;
    const int rb   = bid >> 4;
    const int blkh0 = rb * HB;
    const int gc0   = g * GC;
    const int hq0   = blkh0 + sub * 16 + q * 4;
    const int gi    = (gt * NRB + rb) * 4 + sub;

    if (tid == 0) { s_flag = 0; fdone = 0u; }
    __syncthreads();
    if (tid < 256) {
        if (xk[(size_t)gc0 * Sdim + 2 * tid + 1] != 0) s_flag = 1;
    }
    if (tid < 3 * HB) {
        const int v  = tid >> 6;
        const int hl = tid & 63;
        const int hg = blkh0 + hl;
        float pf = bfv[hg], pi = biv[hg], po = bov[hg], pc = bcv[hg];
        #pragma unroll
        for (int e = 0; e < Edim; ++e) {
            const float ev = emb[v * Edim + e];
            pf += Wfx[hg * Edim + e] * ev;
            pi += Wix[hg * Edim + e] * ev;
            po += Wox[hg * Edim + e] * ev;
            pc += Wcx[hg * Edim + e] * ev;
        }
        float* t = &tbl[(v * HB + hl) * 4];
        t[0] = pf; t[1] = pi; t[2] = po; t[3] = sigf(pc);
    }
    __syncthreads();
    const int is64 = (s_flag == 0);

    {   // tokens -> LDS bytes
        const int col   = tid >> 4;
        const int sbase = (tid & 15) * 16;
        const size_t rowb = (size_t)(gc0 + col) * Sdim;
        for (int k2 = 0; k2 < 16; ++k2) {
            const int s0 = sbase + k2;
            const size_t idx = rowb + s0;
            xtok[col * XSTR + s0] = (unsigned char)xk[is64 ? (idx << 1) : idx];
        }
    }

    // persistent W-hi AND W-lo fragments for this wave's gate/rows
    f16x8 whi[NKK], wlo[NKK];
    #pragma unroll
    for (int kk = 0; kk < NKK; ++kk) {
        whi[kk] = *(const f16x8*)&wpk[((size_t)(gi * NKK + kk) * 64 + lane) * 8];
        wlo[kk] = *(const f16x8*)&wpk[((size_t)WP_FRAGS + (size_t)(gi * NKK + kk) * 64 + lane) * 8];
    }

    // persistent fp32 c state (C-frag layout; used by f-waves)
    float cst[2][4];
    #pragma unroll
    for (int ct = 0; ct < 2; ++ct) {
        const int b = gc0 + ct * 16 + r;
        #pragma unroll
        for (int reg = 0; reg < 4; ++reg)
            cst[ct][reg] = cinit[(size_t)(hq0 + reg) * Bdim + b];
    }

    // step-0 LDS tiles from c_init
    for (int i = 0; i < 48; ++i) {
        const int idx = tid + i * 512;
        const int col = idx & 31, k = idx >> 5;
        const float v = cinit[(size_t)k * Bdim + gc0 + col];
        const _Float16 h = (_Float16)v;
        ldsH[col * CSTR + k] = h;
        ldsM[col * CSTR + k] = (_Float16)((v - (float)h) * SCL);
    }

    for (int s = 0; s < NSTEP; ++s) {
        __syncthreads();                              // S1: tiles ready

        f32x4 a0h = {0,0,0,0}, a0x = {0,0,0,0}, a1h = {0,0,0,0}, a1x = {0,0,0,0};
        #pragma unroll
        for (int kk = 0; kk < NKK; ++kk) {
            const int lo = kk * 32 + q * 8;
            const f16x8 bh0 = *(const f16x8*)&ldsH[ r       * CSTR + lo];
            const f16x8 bm0 = *(const f16x8*)&ldsM[ r       * CSTR + lo];
            const f16x8 bh1 = *(const f16x8*)&ldsH[(16 + r) * CSTR + lo];
            const f16x8 bm1 = *(const f16x8*)&ldsM[(16 + r) * CSTR + lo];
            a0h = mf(whi[kk], bh0, a0h);
            a0x = mf(whi[kk], bm0, a0x);
            a0x = mf(wlo[kk], bh0, a0x);
            a1h = mf(whi[kk], bh1, a1h);
            a1x = mf(whi[kk], bm1, a1x);
            a1x = mf(wlo[kk], bh1, a1x);
        }
        if (gt) {                                     // i-waves export z_i
            #pragma unroll
            for (int ct = 0; ct < 2; ++ct) {
                const f32x4 zh = ct ? a1h : a0h;
                const f32x4 zx = ct ? a1x : a0x;
                #pragma unroll
                for (int reg = 0; reg < 4; ++reg)
                    zbuf[(sub * 16 + q * 4 + reg) * GC + ct * 16 + r] =
                        zh[reg] + zx[reg] * SCL_INV;
            }
        }
        __syncthreads();                              // S2: zbuf ready, tiles dead

        if (!gt) {
            if (s != NSTEP - 1) {
                _Float16* cwH = cbuf + (size_t)(((s + 1) & 1) * 2) * PLANE;
                _Float16* cwM = cwH + PLANE;
                #pragma unroll
                for (int ct = 0; ct < 2; ++ct) {
                    const int bl = ct * 16 + r;
                    const int v  = xtok[bl * XSTR + s];
                    const float* tb = &tbl[(v * HB + sub * 16 + q * 4) * 4];
                    const f32x4 zh = ct ? a1h : a0h;
                    const f32x4 zx = ct ? a1x : a0x;
                    f16x4 cvh, cvm;
                    #pragma unroll
                    for (int reg = 0; reg < 4; ++reg) {
                        const float zf = zh[reg] + zx[reg] * SCL_INV;
                        const float zi = zbuf[(sub * 16 + q * 4 + reg) * GC + bl];
                        const float* tt = tb + reg * 4;
                        const float fg = sigf(zf + tt[0]);
                        const float ig = sigf(zi + tt[1]);
                        const float cn = tt[3] * ig + cst[ct][reg] * fg;
                        cst[ct][reg] = cn;
                        const _Float16 ch = (_Float16)cn;
                        cvh[reg] = ch;
                        cvm[reg] = (_Float16)((cn - (float)ch) * SCL);
                    }
                    unsigned long long uh, um;
                    __builtin_memcpy(&uh, &cvh, 8);
                    __builtin_memcpy(&um, &cvm, 8);
                    const size_t eo = (size_t)(gc0 + bl) * Hdim + hq0;
                    __hip_atomic_store((unsigned long long*)&cwH[eo], uh,
                                       __ATOMIC_RELAXED, __HIP_MEMORY_SCOPE_AGENT);
                    __hip_atomic_store((unsigned long long*)&cwM[eo], um,
                                       __ATOMIC_RELAXED, __HIP_MEMORY_SCOPE_AGENT);
                }
                // drain own stores, then count in; 4th f-wave fires group flag
                asm volatile("s_waitcnt vmcnt(0)" ::: "memory");
                if (lane == 0) {
                    const unsigned old = __hip_atomic_fetch_add(&fdone, 1u,
                                         __ATOMIC_ACQ_REL, __HIP_MEMORY_SCOPE_WORKGROUP);
                    if (old == 4u * (unsigned)s + 3u)
                        __hip_atomic_store(&bar[g * 16 + rb], (unsigned)(s + 1),
                                           __ATOMIC_RELAXED, __HIP_MEMORY_SCOPE_AGENT);
                }
            } else {
                // last step: o-gate from fp32 Woh (hi-only fp16), h = tanh(c)*o
                f32x4 o0h = {0,0,0,0}, o0x = {0,0,0,0}, o1h = {0,0,0,0}, o1x = {0,0,0,0};
                const int arow = blkh0 + sub * 16 + r;
                #pragma unroll
                for (int kk = 0; kk < NKK; ++kk) {
                    const float* wp = Woh + (size_t)arow * Hdim + kk * 32 + q * 8;
                    f16x8 who;
                    #pragma unroll
                    for (int j = 0; j < 8; ++j) who[j] = (_Float16)wp[j];
                    const int lo = kk * 32 + q * 8;
                    const f16x8 bh0 = *(const f16x8*)&ldsH[ r       * CSTR + lo];
                    const f16x8 bm0 = *(const f16x8*)&ldsM[ r       * CSTR + lo];
                    const f16x8 bh1 = *(const f16x8*)&ldsH[(16 + r) * CSTR + lo];
                    const f16x8 bm1 = *(const f16x8*)&ldsM[(16 + r) * CSTR + lo];
                    o0h = mf(who, bh0, o0h);  o0x = mf(who, bm0, o0x);
                    o1h = mf(who, bh1, o1h);  o1x = mf(who, bm1, o1x);
                }
                #pragma unroll
                for (int ct = 0; ct < 2; ++ct) {
                    const int bl = ct * 16 + r;
                    const int v  = xtok[bl * XSTR + s];
                    const float* tb = &tbl[(v * HB + sub * 16 + q * 4) * 4];
                    const f32x4 zh = ct ? a1h : a0h;
                    const f32x4 zx = ct ? a1x : a0x;
                    const f32x4 zoh = ct ? o1h : o0h;
                    const f32x4 zox = ct ? o1x : o0x;
                    f32x4 hv;
                    #pragma unroll
                    for (int reg = 0; reg < 4; ++reg) {
                        const float zf = zh[reg] + zx[reg] * SCL_INV;
                        const float zi = zbuf[(sub * 16 + q * 4 + reg) * GC + bl];
                        const float zo = zoh[reg] + zox[reg] * SCL_INV;
                        const float* tt = tb + reg * 4;
                        const float fg = sigf(zf + tt[0]);
                        const float ig = sigf(zi + tt[1]);
                        const float og = sigf(zo + tt[2]);
                        const float cn = tt[3] * ig + cst[ct][reg] * fg;
                        const float e  = __expf(-2.0f * fabsf(cn));
                        const float th = __builtin_copysignf((1.0f - e) / (1.0f + e), cn);
                        hv[reg] = th * og;
                    }
                    *(f32x4*)&hfin[(size_t)(gc0 + bl) * Hdim + hq0] = hv;
                }
            }
        }

        if (s < NSTEP - 1) {
            // every wave independently: wait for all 12 producer flags
            const unsigned tgt = (unsigned)(s + 1);
            while (true) {
                unsigned vv = tgt;
                if (lane < NRB)
                    vv = __hip_atomic_load(&bar[g * 16 + lane],
                                           __ATOMIC_RELAXED, __HIP_MEMORY_SCOPE_AGENT);
                if (__all(vv >= tgt)) break;
                __builtin_amdgcn_s_sleep(1);
            }
            // stage next c tiles (LLC-coherent loads), 2 passes to cap VGPRs
            const _Float16* crH = cbuf + (size_t)(((s + 1) & 1) * 2) * PLANE;
            const _Float16* crM = crH + PLANE;
            const int col = tid >> 4, j = tid & 15;
            const size_t rowo = (size_t)(gc0 + col) * Hdim;
            {
                unsigned long long th[12];
                #pragma unroll
                for (int i = 0; i < 12; ++i)
                    th[i] = __hip_atomic_load((unsigned long long*)&crH[rowo + (j + 16 * i) * 4],
                                              __ATOMIC_RELAXED, __HIP_MEMORY_SCOPE_AGENT);
                #pragma unroll
                for (int i = 0; i < 12; ++i)
                    *(unsigned long long*)&ldsH[col * CSTR + (j + 16 * i) * 4] = th[i];
            }
            {
                unsigned long long tm[12];
                #pragma unroll
                for (int i = 0; i < 12; ++i)
                    tm[i] = __hip_atomic_load((unsigned long long*)&crM[rowo + (j + 16 * i) * 4],
                                              __ATOMIC_RELAXED, __HIP_MEMORY_SCOPE_AGENT);
                #pragma unroll
                for (int i = 0; i < 12; ++i)
                    *(unsigned long long*)&ldsM[col * CSTR + (j + 16 * i) * 4] = tm[i];
            }
        }
    }
}

__global__ void __launch_bounds__(64)
proj_kernel(const float* __restrict__ hfin, const float* __restrict__ Wph,
            const float* __restrict__ bpv, float* __restrict__ out)
{
    const int b = blockIdx.x;
    const int lane = threadIdx.x;
    float acc[NCls];
    #pragma unroll
    for (int c = 0; c < NCls; ++c) acc[c] = 0.f;
    const float* hb = &hfin[(size_t)b * Hdim];
    for (int i = 0; i < Hdim / 64; ++i) {
        const float hv = hb[lane + i * 64];
        #pragma unroll
        for (int c = 0; c < NCls; ++c)
            acc[c] += Wph[c * Hdim + lane + i * 64] * hv;
    }
    #pragma unroll
    for (int c = 0; c < NCls; ++c) {
        float v = acc[c];
        #pragma unroll
        for (int off = 32; off > 0; off >>= 1)
            v += __shfl_xor(v, off, 64);
        acc[c] = v + bpv[c];
    }
    float m = acc[0];
    #pragma unroll
    for (int c = 1; c < NCls; ++c) m = fmaxf(m, acc[c]);
    float ssum = 0.f;
    #pragma unroll
    for (int c = 0; c < NCls; ++c) ssum += __expf(acc[c] - m);
    const float lse = m + __logf(ssum);
    if (lane < NCls) out[b * NCls + lane] = acc[lane] - lse;
}

extern "C" void kernel_launch(void* const* d_in, const int* in_sizes, int n_in,
                              void* d_out, int out_size, void* d_ws, size_t ws_size,
                              hipStream_t stream)
{
    const int*   xk    = (const int*)d_in[0];
    const float* emb   = (const float*)d_in[1];
    const float* Wfx   = (const float*)d_in[2];
    const float* Wfh   = (const float*)d_in[3];
    const float* bfv   = (const float*)d_in[4];
    const float* Wix   = (const float*)d_in[5];
    const float* Wih   = (const float*)d_in[6];
    const float* biv   = (const float*)d_in[7];
    const float* Wox   = (const float*)d_in[8];
    const float* Woh   = (const float*)d_in[9];
    const float* bov   = (const float*)d_in[10];
    const float* Wcx   = (const float*)d_in[11];
    const float* bcv   = (const float*)d_in[12];
    const float* Wph   = (const float*)d_in[13];
    const float* bpv   = (const float*)d_in[14];
    const float* cinit = (const float*)d_in[15];

    char* ws = (char*)d_ws;
    _Float16*     cbuf = (_Float16*)(ws + WS_CBUF);
    float*        hfin = (float*)(ws + WS_HFIN);
    unsigned int* bar  = (unsigned int*)(ws + WS_BAR);
    _Float16*     wpk  = (_Float16*)(ws + WS_WPK);

    hipMemsetAsync(bar, 0, WS_BAR_BYTES, stream);

    prep_w<<<dim3(WP_FRAGS / 256), dim3(256), 0, stream>>>(Wfh, Wih, wpk);

    lstm_persist<<<dim3(NGRP * NRB), dim3(512), 0, stream>>>(
        xk, emb, Wfx, bfv, Wix, biv, Wox, Woh, bov, Wcx, bcv,
        cinit, wpk, cbuf, hfin, bar);

    proj_kernel<<<dim3(Bdim), dim3(64), 0, stream>>>(hfin, Wph, bpv, (float*)d_out);
}

// Round 5
// 2119.403 us; speedup vs baseline: 1.2183x; 1.2183x over previous
//
#include <hip/hip_runtime.h>

// ---------------------------------------------------------------------------
// peepLSTM (B=512,S=256,H=768,E=6,C=10,V=3) — fp16 split MFMA, fence-free sync
//
//  r5 = r3 structure (proven 2196 us) + W-lo held in VGPRs, with two forcing
//  mechanisms the r4 attempt lacked:
//   * empty inline-asm "+v" keepalive on every W fragment after load —
//     values become asm-defined, rematerialization impossible.
//   * __launch_bounds__(512, 2): min 2 waves/EU -> allocator targets <=256.
//  Barrier/staging identical to r3 (single-variable change vs r3).
// ---------------------------------------------------------------------------

typedef _Float16 f16x8 __attribute__((ext_vector_type(8)));
typedef _Float16 f16x4 __attribute__((ext_vector_type(4)));
typedef float    f32x4 __attribute__((ext_vector_type(4)));

#define Hdim  768
#define Bdim  512
#define Sdim  256
#define NSTEP 255
#define Edim  6
#define NCls  10
#define NGRP  16
#define NRB   12
#define GC    32
#define HB    64
#define NKK   24
#define CSTR  776
#define XSTR  260
#define PLANE (Bdim * Hdim)          // fp16 elems per c plane (393216)
#define SCL      4096.0f
#define SCL_INV  2.44140625e-4f      // 2^-12

#define WP_FRAGS   (2 * NRB * 4 * NKK * 64)         // 147456 fragments (16B each)
#define WS_CBUF    0u                               // 2 bufs x 2 planes x PLANE fp16
#define WS_HFIN    (2u * 2u * PLANE * 2u)           // 3,145,728
#define WS_BAR     (WS_HFIN + Bdim * Hdim * 4u)     // 4,718,592
#define WS_WPK     (WS_BAR + 4096u)                 // 4,722,688
#define WS_BAR_BYTES (NGRP * 16u * 4u)              // 1024

__device__ __forceinline__ float sigf(float z) { return 1.0f / (1.0f + __expf(-z)); }

__device__ __forceinline__ f32x4 mf(f16x8 a, f16x8 b, f32x4 c) {
    return __builtin_amdgcn_mfma_f32_16x16x32_f16(a, b, c, 0, 0, 0);
}

// Force a fragment to stay materialized in VGPRs: the empty asm claims to
// read-modify-write it, so the value is asm-defined and cannot be
// rematerialized from memory by the register allocator.
__device__ __forceinline__ void keepalive(f16x8& x) {
    asm volatile("" : "+v"(x));
}

// ---------------- prep: split W into fp16 hi / (lo*4096) fragment planes ----
__global__ void __launch_bounds__(256)
prep_w(const float* __restrict__ Wfh, const float* __restrict__ Wih,
       _Float16* __restrict__ wpk)
{
    const int fid  = blockIdx.x * 256 + threadIdx.x;   // 0..147455
    const int lane = fid & 63;
    const int t1   = fid >> 6;            // gi*24 + kk
    const int kk   = t1 % NKK;
    const int gi   = t1 / NKK;            // (gate*12+rb)*4+sub
    const int sub  = gi & 3;
    const int t3   = gi >> 2;
    const int rb   = t3 % NRB;
    const int gate = t3 / NRB;
    const int q = lane >> 4, r = lane & 15;
    const int row = rb * 64 + sub * 16 + r;
    const int col = kk * 32 + q * 8;
    const float* src = (gate ? Wih : Wfh) + (size_t)row * Hdim + col;
    f16x8 hi, lo;
    #pragma unroll
    for (int j = 0; j < 8; ++j) {
        const float v = src[j];
        const _Float16 h = (_Float16)v;
        hi[j] = h;
        lo[j] = (_Float16)((v - (float)h) * SCL);
    }
    *(f16x8*)&wpk[(size_t)fid * 8] = hi;
    *(f16x8*)&wpk[((size_t)WP_FRAGS + fid) * 8] = lo;
}

// ---------------- main persistent kernel ------------------------------------
__global__ void __launch_bounds__(512, 2)
lstm_persist(const int* __restrict__ xk, const float* __restrict__ emb,
             const float* __restrict__ Wfx, const float* __restrict__ bfv,
             const float* __restrict__ Wix, const float* __restrict__ biv,
             const float* __restrict__ Wox, const float* __restrict__ Woh,
             const float* __restrict__ bov,
             const float* __restrict__ Wcx, const float* __restrict__ bcv,
             const float* __restrict__ cinit,
             const _Float16* __restrict__ wpk,
             _Float16* __restrict__ cbuf, float* __restrict__ hfin,
             unsigned int* __restrict__ bar)
{
    __shared__ __align__(16) _Float16 ldsH[GC * CSTR];        // 49,664 B
    __shared__ __align__(16) _Float16 ldsM[GC * CSTR];        // 49,664 B
    __shared__ __align__(16) float    tbl[3 * HB * 4];        //  3,072 B
    __shared__ __align__(16) float    zbuf[HB * GC];          //  8,192 B
    __shared__ __align__(4)  unsigned char xtok[GC * XSTR];   //  8,320 B
    __shared__ int s_flag;

    const int tid  = threadIdx.x;
    const int w    = tid >> 6;
    const int lane = tid & 63;
    const int q    = lane >> 4;
    const int r    = lane & 15;
    const int gt   = w >> 2;            // 0 = f-waves, 1 = i-waves
    const int sub  = w & 3;
    const int bid  = blockIdx.x;
    const int g    = bid & 15;
    const int rb   = bid >> 4;
    const int blkh0 = rb * HB;
    const int gc0   = g * GC;
    const int hq0   = blkh0 + sub * 16 + q * 4;
    const int gi    = (gt * NRB + rb) * 4 + sub;

    if (tid == 0) s_flag = 0;
    __syncthreads();
    if (tid < 256) {
        if (xk[(size_t)gc0 * Sdim + 2 * tid + 1] != 0) s_flag = 1;
    }
    if (tid < 3 * HB) {
        const int v  = tid >> 6;
        const int hl = tid & 63;
        const int hg = blkh0 + hl;
        float pf = bfv[hg], pi = biv[hg], po = bov[hg], pc = bcv[hg];
        #pragma unroll
        for (int e = 0; e < Edim; ++e) {
            const float ev = emb[v * Edim + e];
            pf += Wfx[hg * Edim + e] * ev;
            pi += Wix[hg * Edim + e] * ev;
            po += Wox[hg * Edim + e] * ev;
            pc += Wcx[hg * Edim + e] * ev;
        }
        float* t = &tbl[(v * HB + hl) * 4];
        t[0] = pf; t[1] = pi; t[2] = po; t[3] = sigf(pc);
    }
    __syncthreads();
    const int is64 = (s_flag == 0);

    {   // tokens -> LDS bytes
        const int col   = tid >> 4;
        const int sbase = (tid & 15) * 16;
        const size_t rowb = (size_t)(gc0 + col) * Sdim;
        for (int k2 = 0; k2 < 16; ++k2) {
            const int s0 = sbase + k2;
            const size_t idx = rowb + s0;
            xtok[col * XSTR + s0] = (unsigned char)xk[is64 ? (idx << 1) : idx];
        }
    }

    // persistent W-hi AND W-lo fragments, pinned in VGPRs via keepalive
    f16x8 whi[NKK], wlo[NKK];
    #pragma unroll
    for (int kk = 0; kk < NKK; ++kk) {
        whi[kk] = *(const f16x8*)&wpk[((size_t)(gi * NKK + kk) * 64 + lane) * 8];
        wlo[kk] = *(const f16x8*)&wpk[((size_t)WP_FRAGS + (size_t)(gi * NKK + kk) * 64 + lane) * 8];
    }
    #pragma unroll
    for (int kk = 0; kk < NKK; ++kk) {
        keepalive(whi[kk]);
        keepalive(wlo[kk]);
    }

    // persistent fp32 c state (C-frag layout; used by f-waves)
    float cst[2][4];
    #pragma unroll
    for (int ct = 0; ct < 2; ++ct) {
        const int b = gc0 + ct * 16 + r;
        #pragma unroll
        for (int reg = 0; reg < 4; ++reg)
            cst[ct][reg] = cinit[(size_t)(hq0 + reg) * Bdim + b];
    }

    // step-0 LDS tiles from c_init
    for (int i = 0; i < 48; ++i) {
        const int idx = tid + i * 512;
        const int col = idx & 31, k = idx >> 5;
        const float v = cinit[(size_t)k * Bdim + gc0 + col];
        const _Float16 h = (_Float16)v;
        ldsH[col * CSTR + k] = h;
        ldsM[col * CSTR + k] = (_Float16)((v - (float)h) * SCL);
    }

    for (int s = 0; s < NSTEP; ++s) {
        __syncthreads();                              // S1: tiles ready

        f32x4 a0h = {0,0,0,0}, a0x = {0,0,0,0}, a1h = {0,0,0,0}, a1x = {0,0,0,0};
        #pragma unroll
        for (int kk = 0; kk < NKK; ++kk) {
            const int lo = kk * 32 + q * 8;
            const f16x8 bh0 = *(const f16x8*)&ldsH[ r       * CSTR + lo];
            const f16x8 bm0 = *(const f16x8*)&ldsM[ r       * CSTR + lo];
            const f16x8 bh1 = *(const f16x8*)&ldsH[(16 + r) * CSTR + lo];
            const f16x8 bm1 = *(const f16x8*)&ldsM[(16 + r) * CSTR + lo];
            a0h = mf(whi[kk], bh0, a0h);
            a0x = mf(whi[kk], bm0, a0x);
            a0x = mf(wlo[kk], bh0, a0x);
            a1h = mf(whi[kk], bh1, a1h);
            a1x = mf(whi[kk], bm1, a1x);
            a1x = mf(wlo[kk], bh1, a1x);
        }
        if (gt) {                                     // i-waves export z_i
            #pragma unroll
            for (int ct = 0; ct < 2; ++ct) {
                const f32x4 zh = ct ? a1h : a0h;
                const f32x4 zx = ct ? a1x : a0x;
                #pragma unroll
                for (int reg = 0; reg < 4; ++reg)
                    zbuf[(sub * 16 + q * 4 + reg) * GC + ct * 16 + r] =
                        zh[reg] + zx[reg] * SCL_INV;
            }
        }
        __syncthreads();                              // S2: zbuf ready, tiles dead

        if (!gt) {
            if (s != NSTEP - 1) {
                _Float16* cwH = cbuf + (size_t)(((s + 1) & 1) * 2) * PLANE;
                _Float16* cwM = cwH + PLANE;
                #pragma unroll
                for (int ct = 0; ct < 2; ++ct) {
                    const int bl = ct * 16 + r;
                    const int v  = xtok[bl * XSTR + s];
                    const float* tb = &tbl[(v * HB + sub * 16 + q * 4) * 4];
                    const f32x4 zh = ct ? a1h : a0h;
                    const f32x4 zx = ct ? a1x : a0x;
                    f16x4 cvh, cvm;
                    #pragma unroll
                    for (int reg = 0; reg < 4; ++reg) {
                        const float zf = zh[reg] + zx[reg] * SCL_INV;
                        const float zi = zbuf[(sub * 16 + q * 4 + reg) * GC + bl];
                        const float* tt = tb + reg * 4;
                        const float fg = sigf(zf + tt[0]);
                        const float ig = sigf(zi + tt[1]);
                        const float cn = tt[3] * ig + cst[ct][reg] * fg;
                        cst[ct][reg] = cn;
                        const _Float16 ch = (_Float16)cn;
                        cvh[reg] = ch;
                        cvm[reg] = (_Float16)((cn - (float)ch) * SCL);
                    }
                    unsigned long long uh, um;
                    __builtin_memcpy(&uh, &cvh, 8);
                    __builtin_memcpy(&um, &cvm, 8);
                    const size_t eo = (size_t)(gc0 + bl) * Hdim + hq0;
                    __hip_atomic_store((unsigned long long*)&cwH[eo], uh,
                                       __ATOMIC_RELAXED, __HIP_MEMORY_SCOPE_AGENT);
                    __hip_atomic_store((unsigned long long*)&cwM[eo], um,
                                       __ATOMIC_RELAXED, __HIP_MEMORY_SCOPE_AGENT);
                }
            } else {
                // last step: o-gate from fp32 Woh (hi-only fp16), h = tanh(c)*o
                f32x4 o0h = {0,0,0,0}, o0x = {0,0,0,0}, o1h = {0,0,0,0}, o1x = {0,0,0,0};
                const int arow = blkh0 + sub * 16 + r;
                #pragma unroll
                for (int kk = 0; kk < NKK; ++kk) {
                    const float* wp = Woh + (size_t)arow * Hdim + kk * 32 + q * 8;
                    f16x8 who;
                    #pragma unroll
                    for (int j = 0; j < 8; ++j) who[j] = (_Float16)wp[j];
                    const int lo = kk * 32 + q * 8;
                    const f16x8 bh0 = *(const f16x8*)&ldsH[ r       * CSTR + lo];
                    const f16x8 bm0 = *(const f16x8*)&ldsM[ r       * CSTR + lo];
                    const f16x8 bh1 = *(const f16x8*)&ldsH[(16 + r) * CSTR + lo];
                    const f16x8 bm1 = *(const f16x8*)&ldsM[(16 + r) * CSTR + lo];
                    o0h = mf(who, bh0, o0h);  o0x = mf(who, bm0, o0x);
                    o1h = mf(who, bh1, o1h);  o1x = mf(who, bm1, o1x);
                }
                #pragma unroll
                for (int ct = 0; ct < 2; ++ct) {
                    const int bl = ct * 16 + r;
                    const int v  = xtok[bl * XSTR + s];
                    const float* tb = &tbl[(v * HB + sub * 16 + q * 4) * 4];
                    const f32x4 zh = ct ? a1h : a0h;
                    const f32x4 zx = ct ? a1x : a0x;
                    const f32x4 zoh = ct ? o1h : o0h;
                    const f32x4 zox = ct ? o1x : o0x;
                    f32x4 hv;
                    #pragma unroll
                    for (int reg = 0; reg < 4; ++reg) {
                        const float zf = zh[reg] + zx[reg] * SCL_INV;
                        const float zi = zbuf[(sub * 16 + q * 4 + reg) * GC + bl];
                        const float zo = zoh[reg] + zox[reg] * SCL_INV;
                        const float* tt = tb + reg * 4;
                        const float fg = sigf(zf + tt[0]);
                        const float ig = sigf(zi + tt[1]);
                        const float og = sigf(zo + tt[2]);
                        const float cn = tt[3] * ig + cst[ct][reg] * fg;
                        const float e  = __expf(-2.0f * fabsf(cn));
                        const float th = __builtin_copysignf((1.0f - e) / (1.0f + e), cn);
                        hv[reg] = th * og;
                    }
                    *(f32x4*)&hfin[(size_t)(gc0 + bl) * Hdim + hq0] = hv;
                }
            }
        }

        if (s < NSTEP - 1) {
            asm volatile("s_waitcnt vmcnt(0)" ::: "memory");
            __syncthreads();                          // S3: all c stores at LLC
            if (w == 0) {
                if (lane == 0)
                    __hip_atomic_store(&bar[g * 16 + rb], (unsigned)(s + 1),
                                       __ATOMIC_RELAXED, __HIP_MEMORY_SCOPE_AGENT);
                const unsigned tgt = (unsigned)(s + 1);
                while (true) {
                    unsigned vv = tgt;
                    if (lane < NRB)
                        vv = __hip_atomic_load(&bar[g * 16 + lane],
                                               __ATOMIC_RELAXED, __HIP_MEMORY_SCOPE_AGENT);
                    if (__all(vv >= tgt)) break;
                    __builtin_amdgcn_s_sleep(2);
                }
            }
            __syncthreads();                          // S4: barrier passed
            // stage next c tiles (LLC-coherent loads, 24 x 8B per thread)
            const _Float16* crH = cbuf + (size_t)(((s + 1) & 1) * 2) * PLANE;
            const _Float16* crM = crH + PLANE;
            const int col = tid >> 4, j = tid & 15;
            const size_t rowo = (size_t)(gc0 + col) * Hdim;
            {
                unsigned long long th[12];
                #pragma unroll
                for (int i = 0; i < 12; ++i)
                    th[i] = __hip_atomic_load((unsigned long long*)&crH[rowo + (j + 16 * i) * 4],
                                              __ATOMIC_RELAXED, __HIP_MEMORY_SCOPE_AGENT);
                #pragma unroll
                for (int i = 0; i < 12; ++i)
                    *(unsigned long long*)&ldsH[col * CSTR + (j + 16 * i) * 4] = th[i];
            }
            {
                unsigned long long tm[12];
                #pragma unroll
                for (int i = 0; i < 12; ++i)
                    tm[i] = __hip_atomic_load((unsigned long long*)&crM[rowo + (j + 16 * i) * 4],
                                              __ATOMIC_RELAXED, __HIP_MEMORY_SCOPE_AGENT);
                #pragma unroll
                for (int i = 0; i < 12; ++i)
                    *(unsigned long long*)&ldsM[col * CSTR + (j + 16 * i) * 4] = tm[i];
            }
        }
    }
}

__global__ void __launch_bounds__(64)
proj_kernel(const float* __restrict__ hfin, const float* __restrict__ Wph,
            const float* __restrict__ bpv, float* __restrict__ out)
{
    const int b = blockIdx.x;
    const int lane = threadIdx.x;
    float acc[NCls];
    #pragma unroll
    for (int c = 0; c < NCls; ++c) acc[c] = 0.f;
    const float* hb = &hfin[(size_t)b * Hdim];
    for (int i = 0; i < Hdim / 64; ++i) {
        const float hv = hb[lane + i * 64];
        #pragma unroll
        for (int c = 0; c < NCls; ++c)
            acc[c] += Wph[c * Hdim + lane + i * 64] * hv;
    }
    #pragma unroll
    for (int c = 0; c < NCls; ++c) {
        float v = acc[c];
        #pragma unroll
        for (int off = 32; off > 0; off >>= 1)
            v += __shfl_xor(v, off, 64);
        acc[c] = v + bpv[c];
    }
    float m = acc[0];
    #pragma unroll
    for (int c = 1; c < NCls; ++c) m = fmaxf(m, acc[c]);
    float ssum = 0.f;
    #pragma unroll
    for (int c = 0; c < NCls; ++c) ssum += __expf(acc[c] - m);
    const float lse = m + __logf(ssum);
    if (lane < NCls) out[b * NCls + lane] = acc[lane] - lse;
}

extern "C" void kernel_launch(void* const* d_in, const int* in_sizes, int n_in,
                              void* d_out, int out_size, void* d_ws, size_t ws_size,
                              hipStream_t stream)
{
    const int*   xk    = (const int*)d_in[0];
    const float* emb   = (const float*)d_in[1];
    const float* Wfx   = (const float*)d_in[2];
    const float* Wfh   = (const float*)d_in[3];
    const float* bfv   = (const float*)d_in[4];
    const float* Wix   = (const float*)d_in[5];
    const float* Wih   = (const float*)d_in[6];
    const float* biv   = (const float*)d_in[7];
    const float* Wox   = (const float*)d_in[8];
    const float* Woh   = (const float*)d_in[9];
    const float* bov   = (const float*)d_in[10];
    const float* Wcx   = (const float*)d_in[11];
    const float* bcv   = (const float*)d_in[12];
    const float* Wph   = (const float*)d_in[13];
    const float* bpv   = (const float*)d_in[14];
    const float* cinit = (const float*)d_in[15];

    char* ws = (char*)d_ws;
    _Float16*     cbuf = (_Float16*)(ws + WS_CBUF);
    float*        hfin = (float*)(ws + WS_HFIN);
    unsigned int* bar  = (unsigned int*)(ws + WS_BAR);
    _Float16*     wpk  = (_Float16*)(ws + WS_WPK);

    hipMemsetAsync(bar, 0, WS_BAR_BYTES, stream);

    prep_w<<<dim3(WP_FRAGS / 256), dim3(256), 0, stream>>>(Wfh, Wih, wpk);

    lstm_persist<<<dim3(NGRP * NRB), dim3(512), 0, stream>>>(
        xk, emb, Wfx, bfv, Wix, biv, Wox, Woh, bov, Wcx, bcv,
        cinit, wpk, cbuf, hfin, bar);

    proj_kernel<<<dim3(Bdim), dim3(64), 0, stream>>>(hfin, Wph, bpv, (float*)d_out);
}

// Round 6
// 2118.441 us; speedup vs baseline: 1.2189x; 1.0005x over previous
//
#include <hip/hip_runtime.h>

// ---------------------------------------------------------------------------
// peepLSTM (B=512,S=256,H=768,E=6,C=10,V=3) — fp16 split MFMA, fence-free sync
//
//  r6 changes vs r5 (LDS-read-bound fix):
//   * Each wave: 32 rows (two 16-row A-tiles) x K/2 (K-split) — per loaded
//     B fragment 6 MFMAs instead of 3 -> LDS B-reads 768->384 KB/step.
//   * K-half reduction: f-waves swap partner partials via zred (LDS, 16KB);
//     i-waves write per-kh combined partial z_i planes (zbufP, stride 33);
//     f-waves sum both planes in the epilogue. Same 4 syncs/step as r5.
//  Wave map: w = pr*2+kh; pr: 0,1 = f rows 0-31/32-63; 2,3 = i rows.
//  Epilogue tile of f-wave w: 16 rows at sub' = rh*2+kh (same map as r5 w&3).
// ---------------------------------------------------------------------------

typedef _Float16 f16x8 __attribute__((ext_vector_type(8)));
typedef _Float16 f16x4 __attribute__((ext_vector_type(4)));
typedef float    f32x4 __attribute__((ext_vector_type(4)));

#define Hdim  768
#define Bdim  512
#define Sdim  256
#define NSTEP 255
#define Edim  6
#define NCls  10
#define NGRP  16
#define NRB   12
#define GC    32
#define HB    64
#define NKK   24
#define NK2   12            // K-blocks per K-half
#define CSTR  776
#define XSTR  260
#define ZSTR  33            // zbufP row stride (pad)
#define PLANE (Bdim * Hdim)
#define SCL      4096.0f
#define SCL_INV  2.44140625e-4f

#define WP_FRAGS   (2 * NRB * 4 * NKK * 64)
#define WS_CBUF    0u
#define WS_HFIN    (2u * 2u * PLANE * 2u)
#define WS_BAR     (WS_HFIN + Bdim * Hdim * 4u)
#define WS_WPK     (WS_BAR + 4096u)
#define WS_BAR_BYTES (NGRP * 16u * 4u)

__device__ __forceinline__ float sigf(float z) { return 1.0f / (1.0f + __expf(-z)); }

__device__ __forceinline__ f32x4 mf(f16x8 a, f16x8 b, f32x4 c) {
    return __builtin_amdgcn_mfma_f32_16x16x32_f16(a, b, c, 0, 0, 0);
}

__device__ __forceinline__ void keepalive(f16x8& x) {
    asm volatile("" : "+v"(x));
}

// ---------------- prep: split W into fp16 hi / (lo*4096) fragment planes ----
__global__ void __launch_bounds__(256)
prep_w(const float* __restrict__ Wfh, const float* __restrict__ Wih,
       _Float16* __restrict__ wpk)
{
    const int fid  = blockIdx.x * 256 + threadIdx.x;
    const int lane = fid & 63;
    const int t1   = fid >> 6;
    const int kk   = t1 % NKK;
    const int gi   = t1 / NKK;            // (gate*12+rb)*4+sub
    const int sub  = gi & 3;
    const int t3   = gi >> 2;
    const int rb   = t3 % NRB;
    const int gate = t3 / NRB;
    const int q = lane >> 4, r = lane & 15;
    const int row = rb * 64 + sub * 16 + r;
    const int col = kk * 32 + q * 8;
    const float* src = (gate ? Wih : Wfh) + (size_t)row * Hdim + col;
    f16x8 hi, lo;
    #pragma unroll
    for (int j = 0; j < 8; ++j) {
        const float v = src[j];
        const _Float16 h = (_Float16)v;
        hi[j] = h;
        lo[j] = (_Float16)((v - (float)h) * SCL);
    }
    *(f16x8*)&wpk[(size_t)fid * 8] = hi;
    *(f16x8*)&wpk[((size_t)WP_FRAGS + fid) * 8] = lo;
}

// ---------------- main persistent kernel ------------------------------------
__global__ void __launch_bounds__(512, 1)
lstm_persist(const int* __restrict__ xk, const float* __restrict__ emb,
             const float* __restrict__ Wfx, const float* __restrict__ bfv,
             const float* __restrict__ Wix, const float* __restrict__ biv,
             const float* __restrict__ Wox, const float* __restrict__ Woh,
             const float* __restrict__ bov,
             const float* __restrict__ Wcx, const float* __restrict__ bcv,
             const float* __restrict__ cinit,
             const _Float16* __restrict__ wpk,
             _Float16* __restrict__ cbuf, float* __restrict__ hfin,
             unsigned int* __restrict__ bar)
{
    __shared__ __align__(16) _Float16 ldsH[GC * CSTR];        // 49,664 B
    __shared__ __align__(16) _Float16 ldsM[GC * CSTR];        // 49,664 B
    __shared__ __align__(16) float    tbl[3 * HB * 4];        //  3,072 B
    __shared__ __align__(16) float    zred[4 * 4 * 64 * 4];   // 16,384 B (f32x4[4w][4c][64])
    __shared__ __align__(16) float    zbufP[2 * HB * ZSTR];   // 16,896 B
    __shared__ __align__(4)  unsigned char xtok[GC * XSTR];   //  8,320 B
    __shared__ int s_flag;

    const int tid  = threadIdx.x;
    const int w    = tid >> 6;
    const int lane = tid & 63;
    const int q    = lane >> 4;
    const int r    = lane & 15;
    const int kh   = w & 1;             // K-half
    const int pr   = w >> 1;            // 0,1 = f rows 0-31/32-63 ; 2,3 = i
    const int gt   = pr >> 1;           // 0 = f, 1 = i
    const int rh   = pr & 1;            // 32-row half
    const int subp = rh * 2 + kh;       // epilogue 16-row tile (f-waves)
    const int bid  = blockIdx.x;
    const int g    = bid & 15;
    const int rb   = bid >> 4;
    const int blkh0 = rb * HB;
    const int gc0   = g * GC;
    const int hq0   = blkh0 + subp * 16 + q * 4;

    if (tid == 0) s_flag = 0;
    __syncthreads();
    if (tid < 256) {
        if (xk[(size_t)gc0 * Sdim + 2 * tid + 1] != 0) s_flag = 1;
    }
    if (tid < 3 * HB) {
        const int v  = tid >> 6;
        const int hl = tid & 63;
        const int hg = blkh0 + hl;
        float pf = bfv[hg], pi = biv[hg], po = bov[hg], pc = bcv[hg];
        #pragma unroll
        for (int e = 0; e < Edim; ++e) {
            const float ev = emb[v * Edim + e];
            pf += Wfx[hg * Edim + e] * ev;
            pi += Wix[hg * Edim + e] * ev;
            po += Wox[hg * Edim + e] * ev;
            pc += Wcx[hg * Edim + e] * ev;
        }
        float* t = &tbl[(v * HB + hl) * 4];
        t[0] = pf; t[1] = pi; t[2] = po; t[3] = sigf(pc);
    }
    __syncthreads();
    const int is64 = (s_flag == 0);

    {   // tokens -> LDS bytes
        const int col   = tid >> 4;
        const int sbase = (tid & 15) * 16;
        const size_t rowb = (size_t)(gc0 + col) * Sdim;
        for (int k2 = 0; k2 < 16; ++k2) {
            const int s0 = sbase + k2;
            const size_t idx = rowb + s0;
            xtok[col * XSTR + s0] = (unsigned char)xk[is64 ? (idx << 1) : idx];
        }
    }

    // persistent W fragments: 2 sub-tiles (rows rh*32 + s*16) x K-half kh
    f16x8 whi[2][NK2], wlo[2][NK2];
    #pragma unroll
    for (int s2 = 0; s2 < 2; ++s2) {
        const int gis = (gt * NRB + rb) * 4 + (rh * 2 + s2);
        #pragma unroll
        for (int k2 = 0; k2 < NK2; ++k2) {
            const size_t fo = ((size_t)(gis * NKK + kh * NK2 + k2) * 64 + lane) * 8;
            whi[s2][k2] = *(const f16x8*)&wpk[fo];
            wlo[s2][k2] = *(const f16x8*)&wpk[(size_t)WP_FRAGS * 8 + fo];
        }
    }
    #pragma unroll
    for (int s2 = 0; s2 < 2; ++s2)
        #pragma unroll
        for (int k2 = 0; k2 < NK2; ++k2) {
            keepalive(whi[s2][k2]);
            keepalive(wlo[s2][k2]);
        }

    // persistent fp32 c state for this wave's epilogue tile (f-waves use it)
    float cst[2][4];
    #pragma unroll
    for (int ct = 0; ct < 2; ++ct) {
        const int b = gc0 + ct * 16 + r;
        #pragma unroll
        for (int reg = 0; reg < 4; ++reg)
            cst[ct][reg] = cinit[(size_t)(hq0 + reg) * Bdim + b];
    }

    // step-0 LDS tiles from c_init
    for (int i = 0; i < 48; ++i) {
        const int idx = tid + i * 512;
        const int col = idx & 31, k = idx >> 5;
        const float v = cinit[(size_t)k * Bdim + gc0 + col];
        const _Float16 h = (_Float16)v;
        ldsH[col * CSTR + k] = h;
        ldsM[col * CSTR + k] = (_Float16)((v - (float)h) * SCL);
    }

    for (int s = 0; s < NSTEP; ++s) {
        __syncthreads();                              // S1: tiles ready

        f32x4 ah0c0 = {0,0,0,0}, ax0c0 = {0,0,0,0}, ah0c1 = {0,0,0,0}, ax0c1 = {0,0,0,0};
        f32x4 ah1c0 = {0,0,0,0}, ax1c0 = {0,0,0,0}, ah1c1 = {0,0,0,0}, ax1c1 = {0,0,0,0};
        #pragma unroll
        for (int k2 = 0; k2 < NK2; ++k2) {
            const int lo = (kh * NK2 + k2) * 32 + q * 8;
            const f16x8 bh0 = *(const f16x8*)&ldsH[ r       * CSTR + lo];
            const f16x8 bm0 = *(const f16x8*)&ldsM[ r       * CSTR + lo];
            const f16x8 bh1 = *(const f16x8*)&ldsH[(16 + r) * CSTR + lo];
            const f16x8 bm1 = *(const f16x8*)&ldsM[(16 + r) * CSTR + lo];
            ah0c0 = mf(whi[0][k2], bh0, ah0c0);
            ax0c0 = mf(whi[0][k2], bm0, ax0c0);
            ax0c0 = mf(wlo[0][k2], bh0, ax0c0);
            ah1c0 = mf(whi[1][k2], bh0, ah1c0);
            ax1c0 = mf(whi[1][k2], bm0, ax1c0);
            ax1c0 = mf(wlo[1][k2], bh0, ax1c0);
            ah0c1 = mf(whi[0][k2], bh1, ah0c1);
            ax0c1 = mf(whi[0][k2], bm1, ax0c1);
            ax0c1 = mf(wlo[0][k2], bh1, ax0c1);
            ah1c1 = mf(whi[1][k2], bh1, ah1c1);
            ax1c1 = mf(whi[1][k2], bm1, ax1c1);
            ax1c1 = mf(wlo[1][k2], bh1, ax1c1);
        }

        if (gt == 0) {
            // f: send sub = 1-kh partials to partner via zred
            const f32x4 sH0 = kh ? ah0c0 : ah1c0;
            const f32x4 sX0 = kh ? ax0c0 : ax1c0;
            const f32x4 sH1 = kh ? ah0c1 : ah1c1;
            const f32x4 sX1 = kh ? ax0c1 : ax1c1;
            f32x4* zr = (f32x4*)zred;
            zr[(w * 4 + 0) * 64 + lane] = sH0;
            zr[(w * 4 + 1) * 64 + lane] = sX0;
            zr[(w * 4 + 2) * 64 + lane] = sH1;
            zr[(w * 4 + 3) * 64 + lane] = sX1;
        } else {
            // i: write combined (h + x*2^-12) partials for both subs, plane kh
            float* zp = &zbufP[kh * (HB * ZSTR)];
            #pragma unroll
            for (int s2 = 0; s2 < 2; ++s2) {
                const f32x4 h0 = s2 ? ah1c0 : ah0c0;
                const f32x4 x0 = s2 ? ax1c0 : ax0c0;
                const f32x4 h1 = s2 ? ah1c1 : ah0c1;
                const f32x4 x1 = s2 ? ax1c1 : ax0c1;
                #pragma unroll
                for (int reg = 0; reg < 4; ++reg) {
                    const int row = rh * 32 + s2 * 16 + q * 4 + reg;
                    zp[row * ZSTR + r]      = h0[reg] + x0[reg] * SCL_INV;
                    zp[row * ZSTR + 16 + r] = h1[reg] + x1[reg] * SCL_INV;
                }
            }
        }
        __syncthreads();                              // S2: zred/zbufP ready

        if (gt == 0) {
            // reduce: kept sub=kh + partner partial
            const f32x4* zr = (const f32x4*)zred;
            const int pw = w ^ 1;
            const f32x4 pH0 = zr[(pw * 4 + 0) * 64 + lane];
            const f32x4 pX0 = zr[(pw * 4 + 1) * 64 + lane];
            const f32x4 pH1 = zr[(pw * 4 + 2) * 64 + lane];
            const f32x4 pX1 = zr[(pw * 4 + 3) * 64 + lane];
            const f32x4 kH0 = kh ? ah1c0 : ah0c0;
            const f32x4 kX0 = kh ? ax1c0 : ax0c0;
            const f32x4 kH1 = kh ? ah1c1 : ah0c1;
            const f32x4 kX1 = kh ? ax1c1 : ax0c1;
            float zf[2][4];
            #pragma unroll
            for (int reg = 0; reg < 4; ++reg) {
                zf[0][reg] = (kH0[reg] + pH0[reg]) + (kX0[reg] + pX0[reg]) * SCL_INV;
                zf[1][reg] = (kH1[reg] + pH1[reg]) + (kX1[reg] + pX1[reg]) * SCL_INV;
            }
            const int rowl0 = rh * 32 + kh * 16 + q * 4;

            if (s != NSTEP - 1) {
                _Float16* cwH = cbuf + (size_t)(((s + 1) & 1) * 2) * PLANE;
                _Float16* cwM = cwH + PLANE;
                #pragma unroll
                for (int ct = 0; ct < 2; ++ct) {
                    const int bl = ct * 16 + r;
                    const int v  = xtok[bl * XSTR + s];
                    const float* tb = &tbl[(v * HB + subp * 16 + q * 4) * 4];
                    f16x4 cvh, cvm;
                    #pragma unroll
                    for (int reg = 0; reg < 4; ++reg) {
                        const int rowl = rowl0 + reg;
                        const float zi = zbufP[rowl * ZSTR + bl]
                                       + zbufP[HB * ZSTR + rowl * ZSTR + bl];
                        const float* tt = tb + reg * 4;
                        const float fg = sigf(zf[ct][reg] + tt[0]);
                        const float ig = sigf(zi + tt[1]);
                        const float cn = tt[3] * ig + cst[ct][reg] * fg;
                        cst[ct][reg] = cn;
                        const _Float16 ch = (_Float16)cn;
                        cvh[reg] = ch;
                        cvm[reg] = (_Float16)((cn - (float)ch) * SCL);
                    }
                    unsigned long long uh, um;
                    __builtin_memcpy(&uh, &cvh, 8);
                    __builtin_memcpy(&um, &cvm, 8);
                    const size_t eo = (size_t)(gc0 + bl) * Hdim + hq0;
                    __hip_atomic_store((unsigned long long*)&cwH[eo], uh,
                                       __ATOMIC_RELAXED, __HIP_MEMORY_SCOPE_AGENT);
                    __hip_atomic_store((unsigned long long*)&cwM[eo], um,
                                       __ATOMIC_RELAXED, __HIP_MEMORY_SCOPE_AGENT);
                }
            } else {
                // last step: full-K o-gate for this wave's 16 rows
                f32x4 o0h = {0,0,0,0}, o0x = {0,0,0,0}, o1h = {0,0,0,0}, o1x = {0,0,0,0};
                const int arow = blkh0 + subp * 16 + r;
                #pragma unroll
                for (int kk = 0; kk < NKK; ++kk) {
                    const float* wp = Woh + (size_t)arow * Hdim + kk * 32 + q * 8;
                    f16x8 who;
                    #pragma unroll
                    for (int j = 0; j < 8; ++j) who[j] = (_Float16)wp[j];
                    const int lo = kk * 32 + q * 8;
                    const f16x8 bh0 = *(const f16x8*)&ldsH[ r       * CSTR + lo];
                    const f16x8 bm0 = *(const f16x8*)&ldsM[ r       * CSTR + lo];
                    const f16x8 bh1 = *(const f16x8*)&ldsH[(16 + r) * CSTR + lo];
                    const f16x8 bm1 = *(const f16x8*)&ldsM[(16 + r) * CSTR + lo];
                    o0h = mf(who, bh0, o0h);  o0x = mf(who, bm0, o0x);
                    o1h = mf(who, bh1, o1h);  o1x = mf(who, bm1, o1x);
                }
                #pragma unroll
                for (int ct = 0; ct < 2; ++ct) {
                    const int bl = ct * 16 + r;
                    const int v  = xtok[bl * XSTR + s];
                    const float* tb = &tbl[(v * HB + subp * 16 + q * 4) * 4];
                    const f32x4 zoh = ct ? o1h : o0h;
                    const f32x4 zox = ct ? o1x : o0x;
                    f32x4 hv;
                    #pragma unroll
                    for (int reg = 0; reg < 4; ++reg) {
                        const int rowl = rowl0 + reg;
                        const float zi = zbufP[rowl * ZSTR + bl]
                                       + zbufP[HB * ZSTR + rowl * ZSTR + bl];
                        const float zo = zoh[reg] + zox[reg] * SCL_INV;
                        const float* tt = tb + reg * 4;
                        const float fg = sigf(zf[ct][reg] + tt[0]);
                        const float ig = sigf(zi + tt[1]);
                        const float og = sigf(zo + tt[2]);
                        const float cn = tt[3] * ig + cst[ct][reg] * fg;
                        const float e  = __expf(-2.0f * fabsf(cn));
                        const float th = __builtin_copysignf((1.0f - e) / (1.0f + e), cn);
                        hv[reg] = th * og;
                    }
                    *(f32x4*)&hfin[(size_t)(gc0 + bl) * Hdim + hq0] = hv;
                }
            }
        }

        if (s < NSTEP - 1) {
            asm volatile("s_waitcnt vmcnt(0)" ::: "memory");
            __syncthreads();                          // S3: all c stores at LLC
            if (w == 0) {
                if (lane == 0)
                    __hip_atomic_store(&bar[g * 16 + rb], (unsigned)(s + 1),
                                       __ATOMIC_RELAXED, __HIP_MEMORY_SCOPE_AGENT);
                const unsigned tgt = (unsigned)(s + 1);
                while (true) {
                    unsigned vv = tgt;
                    if (lane < NRB)
                        vv = __hip_atomic_load(&bar[g * 16 + lane],
                                               __ATOMIC_RELAXED, __HIP_MEMORY_SCOPE_AGENT);
                    if (__all(vv >= tgt)) break;
                    __builtin_amdgcn_s_sleep(2);
                }
            }
            __syncthreads();                          // S4: barrier passed
            const _Float16* crH = cbuf + (size_t)(((s + 1) & 1) * 2) * PLANE;
            const _Float16* crM = crH + PLANE;
            const int col = tid >> 4, j = tid & 15;
            const size_t rowo = (size_t)(gc0 + col) * Hdim;
            {
                unsigned long long th[12];
                #pragma unroll
                for (int i = 0; i < 12; ++i)
                    th[i] = __hip_atomic_load((unsigned long long*)&crH[rowo + (j + 16 * i) * 4],
                                              __ATOMIC_RELAXED, __HIP_MEMORY_SCOPE_AGENT);
                #pragma unroll
                for (int i = 0; i < 12; ++i)
                    *(unsigned long long*)&ldsH[col * CSTR + (j + 16 * i) * 4] = th[i];
            }
            {
                unsigned long long tm[12];
                #pragma unroll
                for (int i = 0; i < 12; ++i)
                    tm[i] = __hip_atomic_load((unsigned long long*)&crM[rowo + (j + 16 * i) * 4],
                                              __ATOMIC_RELAXED, __HIP_MEMORY_SCOPE_AGENT);
                #pragma unroll
                for (int i = 0; i < 12; ++i)
                    *(unsigned long long*)&ldsM[col * CSTR + (j + 16 * i) * 4] = tm[i];
            }
        }
    }
}

__global__ void __launch_bounds__(64)
proj_kernel(const float* __restrict__ hfin, const float* __restrict__ Wph,
            const float* __restrict__ bpv, float* __restrict__ out)
{
    const int b = blockIdx.x;
    const int lane = threadIdx.x;
    float acc[NCls];
    #pragma unroll
    for (int c = 0; c < NCls; ++c) acc[c] = 0.f;
    const float* hb = &hfin[(size_t)b * Hdim];
    for (int i = 0; i < Hdim / 64; ++i) {
        const float hv = hb[lane + i * 64];
        #pragma unroll
        for (int c = 0; c < NCls; ++c)
            acc[c] += Wph[c * Hdim + lane + i * 64] * hv;
    }
    #pragma unroll
    for (int c = 0; c < NCls; ++c) {
        float v = acc[c];
        #pragma unroll
        for (int off = 32; off > 0; off >>= 1)
            v += __shfl_xor(v, off, 64);
        acc[c] = v + bpv[c];
    }
    float m = acc[0];
    #pragma unroll
    for (int c = 1; c < NCls; ++c) m = fmaxf(m, acc[c]);
    float ssum = 0.f;
    #pragma unroll
    for (int c = 0; c < NCls; ++c) ssum += __expf(acc[c] - m);
    const float lse = m + __logf(ssum);
    if (lane < NCls) out[b * NCls + lane] = acc[lane] - lse;
}

extern "C" void kernel_launch(void* const* d_in, const int* in_sizes, int n_in,
                              void* d_out, int out_size, void* d_ws, size_t ws_size,
                              hipStream_t stream)
{
    const int*   xk    = (const int*)d_in[0];
    const float* emb   = (const float*)d_in[1];
    const float* Wfx   = (const float*)d_in[2];
    const float* Wfh   = (const float*)d_in[3];
    const float* bfv   = (const float*)d_in[4];
    const float* Wix   = (const float*)d_in[5];
    const float* Wih   = (const float*)d_in[6];
    const float* biv   = (const float*)d_in[7];
    const float* Wox   = (const float*)d_in[8];
    const float* Woh   = (const float*)d_in[9];
    const float* bov   = (const float*)d_in[10];
    const float* Wcx   = (const float*)d_in[11];
    const float* bcv   = (const float*)d_in[12];
    const float* Wph   = (const float*)d_in[13];
    const float* bpv   = (const float*)d_in[14];
    const float* cinit = (const float*)d_in[15];

    char* ws = (char*)d_ws;
    _Float16*     cbuf = (_Float16*)(ws + WS_CBUF);
    float*        hfin = (float*)(ws + WS_HFIN);
    unsigned int* bar  = (unsigned int*)(ws + WS_BAR);
    _Float16*     wpk  = (_Float16*)(ws + WS_WPK);

    hipMemsetAsync(bar, 0, WS_BAR_BYTES, stream);

    prep_w<<<dim3(WP_FRAGS / 256), dim3(256), 0, stream>>>(Wfh, Wih, wpk);

    lstm_persist<<<dim3(NGRP * NRB), dim3(512), 0, stream>>>(
        xk, emb, Wfx, bfv, Wix, biv, Wox, Woh, bov, Wcx, bcv,
        cinit, wpk, cbuf, hfin, bar);

    proj_kernel<<<dim3(Bdim), dim3(64), 0, stream>>>(hfin, Wph, bpv, (float*)d_out);
}